// Round 9
// baseline (168.405 us; speedup 1.0000x reference)
//
#include <hip/hip_runtime.h>
#include <hip/hip_bf16.h>
#include <stdint.h>

#define K1 1.4426950408889634f
#define K2 2.8853900817779268f

typedef float f4 __attribute__((ext_vector_type(4)));
typedef float f2 __attribute__((ext_vector_type(2)));
typedef short s8v __attribute__((ext_vector_type(8)));
typedef unsigned int u32;
typedef unsigned short u16;

// workspace offsets (bytes)
#define WS_WCAT  0        // u16[512*192] permuted+concat gate weights (bf16)
#define WS_WG    196608   // u16[64*64]   ln1-folded emb weights, k-padded (bf16)
#define WS_TE    204800   // f32[64]
#define WS_SE    205056   // f32[64]
#define WS_PWLN  205312   // f32[256]  pos_W * ln2_w
#define WS_SPW   206336   // f32[2]
#define WS_PBE   206344   // f32[2]
#define WS_BC    206352   // f32[512]  permuted b_ih+b_hh
#define WS_FLAGS 208400   // int[256] per-block step progress

// LDS sync cells
#define C_WIN 0   // windows staged through v (wave4 lane0)
#define C_RDY 1   // 4*(steps whose x,h are ready) — compute arrivals
#define C_RED 2   // 4*(t+1) stats partials written
#define C_SWP 3   // staging internal, 4/iter
#define C_STT 4   // window stats ready through v (wave4 lane0)
#define C_PRD 5   // steps completed by this block (wv0, after s_self)
#define C_FLG 6   // producer flags confirmed for window v (wave4 lane0)

__device__ __forceinline__ u16 f2bf(float x) {
    u32 u = __builtin_bit_cast(u32, x);
    u32 r = (u + 0x7FFFu + ((u >> 16) & 1u)) >> 16;
    return (u16)r;
}
__device__ __forceinline__ float bf2f(u16 h) {
    u32 u = ((u32)h) << 16;
    return __builtin_bit_cast(float, u);
}

// fast-path check, then sleep-spin: spinning waves must not steal issue
// slots / LDS bandwidth from the working wave on the same SIMD.
__device__ __forceinline__ void waitge(u32* c, u32 v) {
    if (__hip_atomic_load(c, __ATOMIC_ACQUIRE, __HIP_MEMORY_SCOPE_WORKGROUP) >= v) return;
    do {
        __builtin_amdgcn_s_sleep(1);
    } while (__hip_atomic_load(c, __ATOMIC_ACQUIRE, __HIP_MEMORY_SCOPE_WORKGROUP) < v);
}
__device__ __forceinline__ void arrive(u32* c) {
    if ((threadIdx.x & 63) == 0)
        __hip_atomic_fetch_add(c, 1u, __ATOMIC_RELEASE, __HIP_MEMORY_SCOPE_WORKGROUP);
}

__global__ void prep_kernel(const float* __restrict__ ln1w, const float* __restrict__ ln1b,
                            const float* __restrict__ embW, const float* __restrict__ embB,
                            const float* __restrict__ Wih, const float* __restrict__ Whh,
                            const float* __restrict__ bih, const float* __restrict__ bhh,
                            const float* __restrict__ ln2w, const float* __restrict__ ln2b,
                            const float* __restrict__ posW, const float* __restrict__ posB,
                            char* __restrict__ ws) {
    const int tid = threadIdx.x;
    const int bid = blockIdx.x;
    u16* wcat = (u16*)(ws + WS_WCAT);

    if (bid > 0) {
        int base = (bid - 1) * 3072;
#pragma unroll 4
        for (int i = 0; i < 12; ++i) {
            int idx = base + i * 256 + tid;
            int np = idx / 192, k = idx % 192;
            int w = np >> 7, r = np & 127, nt = r >> 4, c = r & 15;
            int g = nt >> 1, jt = nt & 1;
            int n0 = (g << 7) | (w << 5) | (jt << 4) | c;
            float v = (k < 64) ? Wih[n0 * 64 + k] : Whh[n0 * 128 + (k - 64)];
            wcat[idx] = f2bf(v);
        }
        return;
    }

    u16* wg   = (u16*)(ws + WS_WG);
    float* te = (float*)(ws + WS_TE);
    float* se = (float*)(ws + WS_SE);
    float* pwln = (float*)(ws + WS_PWLN);
    float* spw  = (float*)(ws + WS_SPW);
    float* pbe  = (float*)(ws + WS_PBE);
    float* bc   = (float*)(ws + WS_BC);
    int* flags  = (int*)(ws + WS_FLAGS);
    __shared__ float pp[2][4];

    for (int idx = tid; idx < 64 * 64; idx += 256) {
        int e = idx >> 6, k = idx & 63;
        float v = (k < 40) ? embW[e * 40 + k] * ln1w[k] : 0.0f;
        wg[idx] = f2bf(v);
    }
    if (tid < 64) {
        int e = tid;
        float t = embB[e], s = 0.f;
        for (int k = 0; k < 40; ++k) {
            t += embW[e * 40 + k] * ln1b[k];
            s += bf2f(f2bf(embW[e * 40 + k] * ln1w[k]));
        }
        te[e] = t; se[e] = s;
    }
    if (tid >= 64 && tid < 192) {
        int j = tid - 64;
        float a0 = posW[j] * ln2w[j],      a1 = posW[128 + j] * ln2w[j];
        float b0 = posW[j] * ln2b[j],      b1 = posW[128 + j] * ln2b[j];
        pwln[j] = a0; pwln[128 + j] = a1;
#pragma unroll
        for (int m = 1; m < 64; m <<= 1) {
            a0 += __shfl_xor(a0, m, 64); a1 += __shfl_xor(a1, m, 64);
            b0 += __shfl_xor(b0, m, 64); b1 += __shfl_xor(b1, m, 64);
        }
        if ((tid & 63) == 0) {
            int wv = (tid >> 6) - 1;
            pp[wv][0] = a0; pp[wv][1] = a1; pp[wv][2] = b0; pp[wv][3] = b1;
        }
    }
    for (int idx = tid; idx < 512; idx += 256) {
        int w = idx >> 7, r = idx & 127, nt = r >> 4, c = r & 15;
        int g = nt >> 1, jt = nt & 1;
        int n0 = (g << 7) | (w << 5) | (jt << 4) | c;
        bc[idx] = bih[n0] + bhh[n0];
    }
    flags[tid] = 0;
    __syncthreads();
    if (tid == 0) {
        spw[0] = pp[0][0] + pp[1][0];
        spw[1] = pp[0][1] + pp[1][1];
        pbe[0] = posB[0] + pp[0][2] + pp[1][2];
        pbe[1] = posB[1] + pp[0][3] + pp[1][3];
    }
}

__global__ __launch_bounds__(512, 1)
void lstm_kernel(const float* __restrict__ traj_rel,
                 const float* __restrict__ h0, const float* __restrict__ c0,
                 float* __restrict__ dout, char* __restrict__ ws) {
    __shared__ __align__(16) u16 s_whh[12 * 512 * 8];   // 98304 B: W_hh k-chunks 3..5
    __shared__ __align__(16) u16 s_x[2 * 8 * 32 * 8];   // 8192 B
    __shared__ __align__(16) u16 s_h[2 * 16 * 32 * 8];  // 16384 B
    __shared__ __align__(16) u16 s_win[2 * 8 * 32 * 8]; // 8192 B
    __shared__ __align__(16) u16 s_pwb[2048];           // 4096 B : stats B-frags per wave
    __shared__ __align__(16) float s_red1[4][4][32];    // 2048 B : D1 partials [w][n][a]
    __shared__ __align__(16) float s_red2[4][32];       // 512 B  : D2 diag partials
    __shared__ __align__(16) f2 s_wp[320];              // 2560 B
    __shared__ float s_mr[2][32][2];                    // 512 B
    __shared__ float s_self[64];                        // 256 B
    __shared__ u32 s_sync[8];

    const int tid = threadIdx.x;
    const int bk = blockIdx.x;
    const int lane = tid & 63;

    const u16* wcat = (const u16*)(ws + WS_WCAT);
    const u16* wg = (const u16*)(ws + WS_WG);
    int* flags = (int*)(ws + WS_FLAGS);

    if (tid == 0) {
        s_sync[C_WIN] = 0; s_sync[C_RDY] = 0; s_sync[C_RED] = 0;
        s_sync[C_SWP] = 0; s_sync[C_STT] = 0; s_sync[C_PRD] = 0;
        s_sync[C_FLG] = 0;
    }
    // stage W_hh k-chunks 3..5 -> LDS
    for (int idx = tid; idx < 12 * 512; idx += 512) {
        const u16* src = wcat + (idx & 511) * 192 + 96 + (idx >> 9) * 8;
        *(s8v*)(s_whh + idx * 8) = *(const s8v*)src;
    }
    // stats B-frags: [w][ksub][n][8] ; n=0:ones, 1:pwl0, 2:pwl1, 3..:zero
    {
        const float* pwln = (const float*)(ws + WS_PWLN);
        for (int idx = tid; idx < 2048; idx += 512) {
            int w = idx >> 9, rem = idx & 511;
            int ksub = rem >> 7, rem2 = rem & 127;
            int n = rem2 >> 3, i = rem2 & 7;
            int j = 32 * w + ksub * 8 + i;
            float v = (n == 0) ? 1.0f : (n == 1) ? pwln[j] : (n == 2) ? pwln[128 + j] : 0.0f;
            s_pwb[(((w * 4 + ksub) * 16) + n) * 8 + i] = f2bf(v);
        }
    }
    // zero window pad chunks (k=40..63), both buffers
    if (tid < 192) {
        int pb = tid / 96, r = tid % 96;
        int ch = 5 + r / 32, a = r & 31;
        s8v z = {0, 0, 0, 0, 0, 0, 0, 0};
        *(s8v*)(s_win + ((pb * 8 + ch) * 32 + a) * 8) = z;
    }
    // win[0] stage
    if (tid < 320) {
        int p = 1280 * bk + 4 * tid;
        f4 v = *(const f4*)(traj_rel + p);
        int a = tid / 10, kq = (tid % 10) * 4;
        u32 lo = (u32)f2bf(v[0]) | ((u32)f2bf(v[1]) << 16);
        u32 hh = (u32)f2bf(v[2]) | ((u32)f2bf(v[3]) << 16);
        u32* dst = (u32*)(s_win + ((kq >> 3) * 32 + a) * 8 + (kq & 7));
        dst[0] = lo; dst[1] = hh;
        s_wp[tid] = f2{v[0] + v[1] + v[2] + v[3],
                       v[0] * v[0] + v[1] * v[1] + v[2] * v[2] + v[3] * v[3]};
    }
    // h0 -> s_h buffer 0
    if (tid < 256) {
        int a = tid & 31, q = tid >> 5;
        const float* hp = h0 + (bk * 32 + a) * 128 + q * 16;
        u16 hb[16];
#pragma unroll
        for (int u = 0; u < 16; ++u) hb[u] = f2bf(hp[u]);
#pragma unroll
        for (int half = 0; half < 2; ++half) {
            s8v v;
#pragma unroll
            for (int u = 0; u < 8; ++u) v[u] = (short)hb[half * 8 + u];
            *(s8v*)(s_h + ((2 * q + half) * 32 + a) * 8) = v;
        }
    }
    __syncthreads();
    if (tid < 32) {
        float s = 0.f, s2 = 0.f;
#pragma unroll
        for (int u = 0; u < 10; ++u) {
            f2 p = s_wp[tid * 10 + u];
            s += p[0]; s2 += p[1];
        }
        float m = s * (1.0f / 40.0f);
        float var = s2 * (1.0f / 40.0f) - m * m;
        s_mr[0][tid][0] = m;
        s_mr[0][tid][1] = __builtin_amdgcn_rsqf(var + 1e-5f);
    }
    __syncthreads();   // groups diverge below

    if (tid < 256) {
        // ======================= COMPUTE GROUP (waves 0-3) =======================
        __builtin_amdgcn_s_setprio(1);   // favor compute over (sleeping) staging spins
        const int wvi = tid >> 6;
        const int cx = lane & 15;
        const int hi4 = (lane >> 4) * 4;

        s8v wih[8][2], whhr[8];
#pragma unroll
        for (int nt = 0; nt < 8; ++nt) {
            int rowp = 128 * wvi + 16 * nt + cx;
#pragma unroll
            for (int kc = 0; kc < 2; ++kc)
                wih[nt][kc] = *(const s8v*)(wcat + rowp * 192 + kc * 32 + (lane >> 4) * 8);
            whhr[nt] = *(const s8v*)(wcat + rowp * 192 + 64 + (lane >> 4) * 8);
        }
        s8v wgf[2];
#pragma unroll
        for (int kc = 0; kc < 2; ++kc)
            wgf[kc] = *(const s8v*)(wg + (16 * wvi + cx) * 64 + kc * 32 + (lane >> 4) * 8);

        float se_l = ((const float*)(ws + WS_SE))[16 * wvi + cx];
        float te_l = ((const float*)(ws + WS_TE))[16 * wvi + cx];
        float bias[8];
#pragma unroll
        for (int nt = 0; nt < 8; ++nt)
            bias[nt] = ((const float*)(ws + WS_BC))[128 * wvi + 16 * nt + cx];
        float spw0 = ((const float*)(ws + WS_SPW))[0];
        float spw1 = ((const float*)(ws + WS_SPW))[1];
        float pbe0 = ((const float*)(ws + WS_PBE))[0];
        float pbe1 = ((const float*)(ws + WS_PBE))[1];

        float creg[2][2][4];
#pragma unroll
        for (int mt = 0; mt < 2; ++mt)
#pragma unroll
            for (int jt = 0; jt < 2; ++jt)
#pragma unroll
                for (int rg = 0; rg < 4; ++rg)
                    creg[mt][jt][rg] = c0[(bk * 32 + 16 * mt + hi4 + rg) * 128 + 32 * wvi + 16 * jt + cx];

        // pre-loop: emb(0) on window 0 (already staged)
        {
            f4 accE[2];
            accE[0] = f4{0.f, 0.f, 0.f, 0.f};
            accE[1] = f4{0.f, 0.f, 0.f, 0.f};
#pragma unroll
            for (int kc = 0; kc < 2; ++kc)
#pragma unroll
                for (int mt = 0; mt < 2; ++mt) {
                    s8v a = *(const s8v*)(s_win + ((kc * 4 + (lane >> 4)) * 32 + 16 * mt + cx) * 8);
                    accE[mt] = __builtin_amdgcn_mfma_f32_16x16x32_bf16(a, wgf[kc], accE[mt], 0, 0, 0);
                }
            int e = 16 * wvi + cx;
#pragma unroll
            for (int mt = 0; mt < 2; ++mt)
#pragma unroll
                for (int rg = 0; rg < 4; ++rg) {
                    int a = 16 * mt + hi4 + rg;
                    float m = s_mr[0][a][0], r = s_mr[0][a][1];
                    float x = r * (accE[mt][rg] - m * se_l) + te_l;
                    x = fmaxf(x, 0.f) + 0.01f * fminf(x, 0.f);
                    s_x[((e >> 3) * 32 + a) * 8 + (e & 7)] = f2bf(x);
                }
            arrive(&s_sync[C_RDY]);
        }

#pragma unroll 1
        for (int t = 0; t < 30; ++t) {
            const int pc = t & 1, pn = pc ^ 1;
            waitge(&s_sync[C_RDY], (u32)(4 * (t + 1)));   // x(t),h(t) ready

            // gates GEMM in 2 jt-passes; pointwise fused per pass
#pragma unroll
            for (int jt = 0; jt < 2; ++jt) {
                f4 acc[2][4];
#pragma unroll
                for (int mt = 0; mt < 2; ++mt)
#pragma unroll
                    for (int g = 0; g < 4; ++g) {
                        float b = bias[2 * g + jt];
                        acc[mt][g] = f4{b, b, b, b};
                    }
#pragma unroll
                for (int kc = 0; kc < 6; ++kc) {
                    s8v a0, a1;
                    if (kc < 2) {
                        a0 = *(const s8v*)(s_x + ((pc * 8 + kc * 4 + (lane >> 4)) * 32 + cx) * 8);
                        a1 = *(const s8v*)(s_x + ((pc * 8 + kc * 4 + (lane >> 4)) * 32 + 16 + cx) * 8);
                    } else {
                        int ch = (kc - 2) * 4 + (lane >> 4);
                        a0 = *(const s8v*)(s_h + ((pc * 16 + ch) * 32 + cx) * 8);
                        a1 = *(const s8v*)(s_h + ((pc * 16 + ch) * 32 + 16 + cx) * 8);
                    }
#pragma unroll
                    for (int g = 0; g < 4; ++g) {
                        int nt = 2 * g + jt;
                        s8v b;
                        if (kc < 2) b = wih[nt][kc];
                        else if (kc == 2) b = whhr[nt];
                        else b = *(const s8v*)(s_whh + (((kc - 3) * 4 + (lane >> 4)) * 512 + 128 * wvi + 16 * nt + cx) * 8);
                        acc[0][g] = __builtin_amdgcn_mfma_f32_16x16x32_bf16(a0, b, acc[0][g], 0, 0, 0);
                        acc[1][g] = __builtin_amdgcn_mfma_f32_16x16x32_bf16(a1, b, acc[1][g], 0, 0, 0);
                    }
                }
                // LSTM pointwise for this jt -> creg, h(t+1) into s_h[pn]
                int kk = 32 * wvi + 16 * jt + cx;
                int ch = pn * 16 + (kk >> 3);
#pragma unroll
                for (int mt = 0; mt < 2; ++mt)
#pragma unroll
                    for (int rg = 0; rg < 4; ++rg) {
                        float iv = acc[mt][0][rg];
                        float fv = acc[mt][1][rg];
                        float gv = acc[mt][2][rg];
                        float ov = acc[mt][3][rg];
                        float si = __builtin_amdgcn_rcpf(1.f + __builtin_amdgcn_exp2f(-K1 * iv));
                        float sf = __builtin_amdgcn_rcpf(1.f + __builtin_amdgcn_exp2f(-K1 * fv));
                        float so = __builtin_amdgcn_rcpf(1.f + __builtin_amdgcn_exp2f(-K1 * ov));
                        float tg = 1.f - 2.f * __builtin_amdgcn_rcpf(1.f + __builtin_amdgcn_exp2f(K2 * gv));
                        float cn = sf * creg[mt][jt][rg] + si * tg;
                        creg[mt][jt][rg] = cn;
                        float tc = 1.f - 2.f * __builtin_amdgcn_rcpf(1.f + __builtin_amdgcn_exp2f(K2 * cn));
                        float hn = so * tc;
                        int a = 16 * mt + hi4 + rg;
                        s_h[(ch * 32 + a) * 8 + (cx & 7)] = f2bf(hn);
                    }
            }

            // stats via MFMA on own 32-col h slice (just written, same wave)
            {
                f4 d1[2], d2[2];
                d1[0] = f4{0.f, 0.f, 0.f, 0.f}; d1[1] = f4{0.f, 0.f, 0.f, 0.f};
                d2[0] = f4{0.f, 0.f, 0.f, 0.f}; d2[1] = f4{0.f, 0.f, 0.f, 0.f};
                s8v bfrag = *(const s8v*)(s_pwb + ((wvi * 4 + (lane >> 4)) * 16 + cx) * 8);
#pragma unroll
                for (int mt = 0; mt < 2; ++mt) {
                    s8v hf = *(const s8v*)(s_h + ((pn * 16 + 4 * wvi + (lane >> 4)) * 32 + 16 * mt + cx) * 8);
                    d1[mt] = __builtin_amdgcn_mfma_f32_16x16x32_bf16(hf, bfrag, d1[mt], 0, 0, 0);
                    d2[mt] = __builtin_amdgcn_mfma_f32_16x16x32_bf16(hf, hf, d2[mt], 0, 0, 0);
                }
#pragma unroll
                for (int mt = 0; mt < 2; ++mt) {
                    if (cx < 3) {
#pragma unroll
                        for (int rg = 0; rg < 4; ++rg)
                            s_red1[wvi][cx][mt * 16 + hi4 + rg] = d1[mt][rg];
                    }
                    if ((lane >> 4) == (cx >> 2))
                        s_red2[wvi][mt * 16 + cx] = d2[mt][cx & 3];
                }
            }
            arrive(&s_sync[C_RED]);

            // wv0: combine + s_self/C_PRD + dout store ISSUE (drain deferred
            // past emb so the vmcnt(0) overlaps compute instead of blocking it)
            if (wvi == 0) {
                waitge(&s_sync[C_RED], (u32)(4 * (t + 1)));
                int a = lane & 31, d = lane >> 5;
                float S0 = 0.f, S1 = 0.f, P = 0.f;
#pragma unroll
                for (int w = 0; w < 4; ++w) {
                    S0 += s_red1[w][0][a];
                    P  += s_red1[w][1 + d][a];
                    S1 += s_red2[w][a];
                }
                float m = S0 * (1.f / 128.f);
                float var = S1 * (1.f / 128.f) - m * m;
                float r = __builtin_amdgcn_rsqf(var + 1e-5f);
                float sp = (d == 0) ? spw0 : spw1;
                float pb = (d == 0) ? pbe0 : pbe1;
                float val = r * (P - m * sp) + pb;
                s_self[2 * a + d] = val;
                if (tid == 0)
                    __hip_atomic_store(&s_sync[C_PRD], (u32)(t + 1), __ATOMIC_RELEASE, __HIP_MEMORY_SCOPE_WORKGROUP);
                __hip_atomic_store(dout + (t * 8192 + bk * 32 + a) * 2 + d, val,
                                   __ATOMIC_RELAXED, __HIP_MEMORY_SCOPE_AGENT);
                // no vmcnt here — drained after emb below
            }

            // emb(t+1) (pipelined; waits only on staging counters)
            if (t < 29) {
                waitge(&s_sync[C_WIN], (u32)(t + 1));
                waitge(&s_sync[C_STT], (u32)(t + 1));
                f4 accE[2];
                accE[0] = f4{0.f, 0.f, 0.f, 0.f};
                accE[1] = f4{0.f, 0.f, 0.f, 0.f};
#pragma unroll
                for (int kc = 0; kc < 2; ++kc)
#pragma unroll
                    for (int mt = 0; mt < 2; ++mt) {
                        s8v a = *(const s8v*)(s_win + ((pn * 8 + kc * 4 + (lane >> 4)) * 32 + 16 * mt + cx) * 8);
                        accE[mt] = __builtin_amdgcn_mfma_f32_16x16x32_bf16(a, wgf[kc], accE[mt], 0, 0, 0);
                    }
                int e = 16 * wvi + cx;
#pragma unroll
                for (int mt = 0; mt < 2; ++mt)
#pragma unroll
                    for (int rg = 0; rg < 4; ++rg) {
                        int a = 16 * mt + hi4 + rg;
                        float m = s_mr[pn][a][0], r = s_mr[pn][a][1];
                        float x = r * (accE[mt][rg] - m * se_l) + te_l;
                        x = fmaxf(x, 0.f) + 0.01f * fminf(x, 0.f);
                        s_x[((pn * 8 + (e >> 3)) * 32 + a) * 8 + (e & 7)] = f2bf(x);
                    }
            }
            arrive(&s_sync[C_RDY]);

            // wv0 tail: drain dout stores, then publish cross-block flag
            if (wvi == 0) {
                asm volatile("s_waitcnt vmcnt(0)" ::: "memory");
                if (tid == 0)
                    __hip_atomic_store(&flags[bk], t + 1, __ATOMIC_RELAXED, __HIP_MEMORY_SCOPE_AGENT);
            }
        }
    } else {
        // ======================= STAGING GROUP (waves 4-7) =======================
        const int gt = tid - 256;

        auto stage_one = [&](int ci, int s, int pb) {
            int p = 16384 * s + 1280 * bk + 4 * ci;
            float v0, v1, v2, v3;
            if (p < 327680) {
                f4 vv = *(const f4*)(traj_rel + p);
                v0 = vv[0]; v1 = vv[1]; v2 = vv[2]; v3 = vv[3];
            } else if (bk == 255 && ci >= 304) {
                waitge(&s_sync[C_PRD], (u32)s);
                int o = 4 * ci - 1216;
                v0 = s_self[o]; v1 = s_self[o + 1]; v2 = s_self[o + 2]; v3 = s_self[o + 3];
            } else {
                waitge(&s_sync[C_FLG], (u32)s);
                int q = p - 327680;
                f4 vv = *(const f4*)(dout + q);
                v0 = vv[0]; v1 = vv[1]; v2 = vv[2]; v3 = vv[3];
            }
            int a = ci / 10, kq = (ci % 10) * 4;
            u32 lo = (u32)f2bf(v0) | ((u32)f2bf(v1) << 16);
            u32 hh = (u32)f2bf(v2) | ((u32)f2bf(v3) << 16);
            u32* dst = (u32*)(s_win + ((pb * 8 + (kq >> 3)) * 32 + a) * 8 + (kq & 7));
            dst[0] = lo; dst[1] = hh;
            s_wp[ci] = f2{v0 + v1 + v2 + v3, v0 * v0 + v1 * v1 + v2 * v2 + v3 * v3};
        };

#pragma unroll 1
        for (int u = 0; u < 29; ++u) {
            const int pb = (u + 1) & 1;
            waitge(&s_sync[C_STT], (u32)u);          // s_wp free
            waitge(&s_sync[C_RDY], (u32)(4 * u));    // win/mr buffer free (emb(u-1) done)

            if (gt < 64) {
                int W0n = 16384 * (u + 1) + 1280 * bk;
                int Wend = W0n + 1280;
                if (Wend > 327680) {
                    int q0 = (W0n > 327680) ? (W0n - 327680) : 0;
                    int g = (q0 >> 6) + gt;
                    int gend = (Wend - 327681) >> 6;
                    if (g <= gend) {
                        int s = g >> 8, P = g & 255;
                        if (!(bk == 255 && P == 255)) {
                            while (__hip_atomic_load(&flags[P], __ATOMIC_RELAXED, __HIP_MEMORY_SCOPE_AGENT) <= s)
                                __builtin_amdgcn_s_sleep(2);
                        }
                    }
                }
                if (gt == 0)
                    __hip_atomic_store(&s_sync[C_FLG], (u32)(u + 1), __ATOMIC_RELEASE, __HIP_MEMORY_SCOPE_WORKGROUP);
            }

            stage_one(gt, u + 1, pb);
            if (gt < 64) stage_one(gt + 256, u + 1, pb);

            arrive(&s_sync[C_SWP]);
            if (gt < 64) {
                waitge(&s_sync[C_SWP], (u32)(4 * (u + 1)));
                if (gt == 0)
                    __hip_atomic_store(&s_sync[C_WIN], (u32)(u + 1), __ATOMIC_RELEASE, __HIP_MEMORY_SCOPE_WORKGROUP);
                if (gt < 32) {
                    float s = 0.f, s2 = 0.f;
#pragma unroll
                    for (int u2 = 0; u2 < 10; ++u2) {
                        f2 pp = s_wp[gt * 10 + u2];
                        s += pp[0]; s2 += pp[1];
                    }
                    float m = s * (1.0f / 40.0f);
                    float var = s2 * (1.0f / 40.0f) - m * m;
                    s_mr[pb][gt][0] = m;
                    s_mr[pb][gt][1] = __builtin_amdgcn_rsqf(var + 1e-5f);
                }
                if (gt == 0)
                    __hip_atomic_store(&s_sync[C_STT], (u32)(u + 1), __ATOMIC_RELEASE, __HIP_MEMORY_SCOPE_WORKGROUP);
            }
        }
    }
}

extern "C" void kernel_launch(void* const* d_in, const int* in_sizes, int n_in,
                              void* d_out, int out_size, void* d_ws, size_t ws_size,
                              hipStream_t stream) {
    (void)in_sizes; (void)n_in; (void)out_size; (void)ws_size;
    const float* traj_rel = (const float*)d_in[1];
    const float* h0 = (const float*)d_in[2];
    const float* c0 = (const float*)d_in[3];
    const float* ln1w = (const float*)d_in[4];
    const float* ln1b = (const float*)d_in[5];
    const float* embW = (const float*)d_in[6];
    const float* embB = (const float*)d_in[7];
    const float* Wih = (const float*)d_in[8];
    const float* Whh = (const float*)d_in[9];
    const float* bih = (const float*)d_in[10];
    const float* bhh = (const float*)d_in[11];
    const float* ln2w = (const float*)d_in[12];
    const float* ln2b = (const float*)d_in[13];
    const float* posW = (const float*)d_in[14];
    const float* posB = (const float*)d_in[15];
    char* ws = (char*)d_ws;

    hipLaunchKernelGGL(prep_kernel, dim3(33), dim3(256), 0, stream,
                       ln1w, ln1b, embW, embB, Wih, Whh, bih, bhh, ln2w, ln2b, posW, posB, ws);
    hipLaunchKernelGGL(lstm_kernel, dim3(256), dim3(512), 0, stream,
                       traj_rel, h0, c0, (float*)d_out, ws);
}

// Round 10
// 143.886 us; speedup vs baseline: 1.1704x; 1.1704x over previous
//
#include <hip/hip_runtime.h>
#include <hip/hip_bf16.h>
#include <stdint.h>

#define K1 1.4426950408889634f
#define K2 2.8853900817779268f

typedef float f4 __attribute__((ext_vector_type(4)));
typedef float f2 __attribute__((ext_vector_type(2)));
typedef short s8v __attribute__((ext_vector_type(8)));
typedef unsigned int u32;
typedef unsigned short u16;

// workspace offsets (bytes)
#define WS_WCAT  0        // u16[512*192] permuted+concat gate weights (bf16)
#define WS_WG    196608   // u16[64*64]   ln1-folded emb weights, k-padded (bf16)
#define WS_TE    204800   // f32[64]
#define WS_SE    205056   // f32[64]
#define WS_PWLN  205312   // f32[256]  pos_W * ln2_w
#define WS_SPW   206336   // f32[2]
#define WS_PBE   206344   // f32[2]
#define WS_BC    206352   // f32[512]  permuted b_ih+b_hh
#define WS_FLAGS 208400   // int[256] per-block step progress

// LDS sync cells
#define C_WIN 0   // windows staged through v (wave4 lane0)
#define C_RDY 1   // 4*(steps whose x,h are ready) — compute arrivals
#define C_RED 2   // 4*(t+1) stats partials written
#define C_SWP 3   // staging internal, 4/iter
#define C_STT 4   // window stats ready through v (wave4 lane0)
#define C_PRD 5   // steps whose outputs are in s_self (wv0)
#define C_FLG 6   // producer flags confirmed for window v (wave4 lane0)

__device__ __forceinline__ u16 f2bf(float x) {
    u32 u = __builtin_bit_cast(u32, x);
    u32 r = (u + 0x7FFFu + ((u >> 16) & 1u)) >> 16;
    return (u16)r;
}
__device__ __forceinline__ float bf2f(u16 h) {
    u32 u = ((u32)h) << 16;
    return __builtin_bit_cast(float, u);
}

__device__ __forceinline__ void waitge(u32* c, u32 v) {
    while (__hip_atomic_load(c, __ATOMIC_ACQUIRE, __HIP_MEMORY_SCOPE_WORKGROUP) < v) {}
}
__device__ __forceinline__ void arrive(u32* c) {
    if ((threadIdx.x & 63) == 0)
        __hip_atomic_fetch_add(c, 1u, __ATOMIC_RELEASE, __HIP_MEMORY_SCOPE_WORKGROUP);
}

__global__ void prep_kernel(const float* __restrict__ ln1w, const float* __restrict__ ln1b,
                            const float* __restrict__ embW, const float* __restrict__ embB,
                            const float* __restrict__ Wih, const float* __restrict__ Whh,
                            const float* __restrict__ bih, const float* __restrict__ bhh,
                            const float* __restrict__ ln2w, const float* __restrict__ ln2b,
                            const float* __restrict__ posW, const float* __restrict__ posB,
                            char* __restrict__ ws) {
    const int tid = threadIdx.x;
    const int bid = blockIdx.x;
    u16* wcat = (u16*)(ws + WS_WCAT);

    if (bid > 0) {
        int base = (bid - 1) * 3072;
#pragma unroll 4
        for (int i = 0; i < 12; ++i) {
            int idx = base + i * 256 + tid;
            int np = idx / 192, k = idx % 192;
            int w = np >> 7, r = np & 127, nt = r >> 4, c = r & 15;
            int g = nt >> 1, jt = nt & 1;
            int n0 = (g << 7) | (w << 5) | (jt << 4) | c;
            float v = (k < 64) ? Wih[n0 * 64 + k] : Whh[n0 * 128 + (k - 64)];
            wcat[idx] = f2bf(v);
        }
        return;
    }

    u16* wg   = (u16*)(ws + WS_WG);
    float* te = (float*)(ws + WS_TE);
    float* se = (float*)(ws + WS_SE);
    float* pwln = (float*)(ws + WS_PWLN);
    float* spw  = (float*)(ws + WS_SPW);
    float* pbe  = (float*)(ws + WS_PBE);
    float* bc   = (float*)(ws + WS_BC);
    int* flags  = (int*)(ws + WS_FLAGS);
    __shared__ float pp[2][4];

    for (int idx = tid; idx < 64 * 64; idx += 256) {
        int e = idx >> 6, k = idx & 63;
        float v = (k < 40) ? embW[e * 40 + k] * ln1w[k] : 0.0f;
        wg[idx] = f2bf(v);
    }
    if (tid < 64) {
        int e = tid;
        float t = embB[e], s = 0.f;
        for (int k = 0; k < 40; ++k) {
            t += embW[e * 40 + k] * ln1b[k];
            s += bf2f(f2bf(embW[e * 40 + k] * ln1w[k]));
        }
        te[e] = t; se[e] = s;
    }
    if (tid >= 64 && tid < 192) {
        int j = tid - 64;
        float a0 = posW[j] * ln2w[j],      a1 = posW[128 + j] * ln2w[j];
        float b0 = posW[j] * ln2b[j],      b1 = posW[128 + j] * ln2b[j];
        pwln[j] = a0; pwln[128 + j] = a1;
#pragma unroll
        for (int m = 1; m < 64; m <<= 1) {
            a0 += __shfl_xor(a0, m, 64); a1 += __shfl_xor(a1, m, 64);
            b0 += __shfl_xor(b0, m, 64); b1 += __shfl_xor(b1, m, 64);
        }
        if ((tid & 63) == 0) {
            int wv = (tid >> 6) - 1;
            pp[wv][0] = a0; pp[wv][1] = a1; pp[wv][2] = b0; pp[wv][3] = b1;
        }
    }
    for (int idx = tid; idx < 512; idx += 256) {
        int w = idx >> 7, r = idx & 127, nt = r >> 4, c = r & 15;
        int g = nt >> 1, jt = nt & 1;
        int n0 = (g << 7) | (w << 5) | (jt << 4) | c;
        bc[idx] = bih[n0] + bhh[n0];
    }
    flags[tid] = 0;
    __syncthreads();
    if (tid == 0) {
        spw[0] = pp[0][0] + pp[1][0];
        spw[1] = pp[0][1] + pp[1][1];
        pbe[0] = posB[0] + pp[0][2] + pp[1][2];
        pbe[1] = posB[1] + pp[0][3] + pp[1][3];
    }
}

__global__ __launch_bounds__(512, 1)
void lstm_kernel(const float* __restrict__ traj_rel,
                 const float* __restrict__ h0, const float* __restrict__ c0,
                 float* __restrict__ dout, char* __restrict__ ws) {
    __shared__ __align__(16) u16 s_whh[12 * 512 * 8];   // 98304 B: W_hh k-chunks 3..5
    __shared__ __align__(16) u16 s_x[2 * 8 * 32 * 8];   // 8192 B
    __shared__ __align__(16) u16 s_h[2 * 16 * 32 * 8];  // 16384 B
    __shared__ __align__(16) u16 s_win[2 * 8 * 32 * 8]; // 8192 B
    __shared__ __align__(16) u16 s_pwb[2048];           // 4096 B : stats B-frags per wave
    __shared__ __align__(16) float s_red1[4][4][32];    // 2048 B : D1 partials [w][n][a]
    __shared__ __align__(16) float s_red2[4][32];       // 512 B  : D2 diag partials
    __shared__ __align__(16) f2 s_wp[320];              // 2560 B
    __shared__ float s_mr[2][32][2];                    // 512 B
    __shared__ float s_self[2][64];                     // 512 B : step outputs (dbuf)
    __shared__ u32 s_sync[8];

    const int tid = threadIdx.x;
    const int bk = blockIdx.x;
    const int lane = tid & 63;

    const u16* wcat = (const u16*)(ws + WS_WCAT);
    const u16* wg = (const u16*)(ws + WS_WG);
    int* flags = (int*)(ws + WS_FLAGS);

    if (tid == 0) {
        s_sync[C_WIN] = 0; s_sync[C_RDY] = 0; s_sync[C_RED] = 0;
        s_sync[C_SWP] = 0; s_sync[C_STT] = 0; s_sync[C_PRD] = 0;
        s_sync[C_FLG] = 0;
    }
    // stage W_hh k-chunks 3..5 -> LDS
    for (int idx = tid; idx < 12 * 512; idx += 512) {
        const u16* src = wcat + (idx & 511) * 192 + 96 + (idx >> 9) * 8;
        *(s8v*)(s_whh + idx * 8) = *(const s8v*)src;
    }
    // stats B-frags: [w][ksub][n][8] ; n=0:ones, 1:pwl0, 2:pwl1, 3..:zero
    {
        const float* pwln = (const float*)(ws + WS_PWLN);
        for (int idx = tid; idx < 2048; idx += 512) {
            int w = idx >> 9, rem = idx & 511;
            int ksub = rem >> 7, rem2 = rem & 127;
            int n = rem2 >> 3, i = rem2 & 7;
            int j = 32 * w + ksub * 8 + i;
            float v = (n == 0) ? 1.0f : (n == 1) ? pwln[j] : (n == 2) ? pwln[128 + j] : 0.0f;
            s_pwb[(((w * 4 + ksub) * 16) + n) * 8 + i] = f2bf(v);
        }
    }
    // zero window pad chunks (k=40..63), both buffers
    if (tid < 192) {
        int pb = tid / 96, r = tid % 96;
        int ch = 5 + r / 32, a = r & 31;
        s8v z = {0, 0, 0, 0, 0, 0, 0, 0};
        *(s8v*)(s_win + ((pb * 8 + ch) * 32 + a) * 8) = z;
    }
    // win[0] stage
    if (tid < 320) {
        int p = 1280 * bk + 4 * tid;
        f4 v = *(const f4*)(traj_rel + p);
        int a = tid / 10, kq = (tid % 10) * 4;
        u32 lo = (u32)f2bf(v[0]) | ((u32)f2bf(v[1]) << 16);
        u32 hh = (u32)f2bf(v[2]) | ((u32)f2bf(v[3]) << 16);
        u32* dst = (u32*)(s_win + ((kq >> 3) * 32 + a) * 8 + (kq & 7));
        dst[0] = lo; dst[1] = hh;
        s_wp[tid] = f2{v[0] + v[1] + v[2] + v[3],
                       v[0] * v[0] + v[1] * v[1] + v[2] * v[2] + v[3] * v[3]};
    }
    // h0 -> s_h buffer 0
    if (tid < 256) {
        int a = tid & 31, q = tid >> 5;
        const float* hp = h0 + (bk * 32 + a) * 128 + q * 16;
        u16 hb[16];
#pragma unroll
        for (int u = 0; u < 16; ++u) hb[u] = f2bf(hp[u]);
#pragma unroll
        for (int half = 0; half < 2; ++half) {
            s8v v;
#pragma unroll
            for (int u = 0; u < 8; ++u) v[u] = (short)hb[half * 8 + u];
            *(s8v*)(s_h + ((2 * q + half) * 32 + a) * 8) = v;
        }
    }
    __syncthreads();
    if (tid < 32) {
        float s = 0.f, s2 = 0.f;
#pragma unroll
        for (int u = 0; u < 10; ++u) {
            f2 p = s_wp[tid * 10 + u];
            s += p[0]; s2 += p[1];
        }
        float m = s * (1.0f / 40.0f);
        float var = s2 * (1.0f / 40.0f) - m * m;
        s_mr[0][tid][0] = m;
        s_mr[0][tid][1] = __builtin_amdgcn_rsqf(var + 1e-5f);
    }
    __syncthreads();   // groups diverge below

    if (tid < 256) {
        // ======================= COMPUTE GROUP (waves 0-3) =======================
        const int wvi = tid >> 6;
        const int cx = lane & 15;
        const int hi4 = (lane >> 4) * 4;

        s8v wih[8][2], whhr[8];
#pragma unroll
        for (int nt = 0; nt < 8; ++nt) {
            int rowp = 128 * wvi + 16 * nt + cx;
#pragma unroll
            for (int kc = 0; kc < 2; ++kc)
                wih[nt][kc] = *(const s8v*)(wcat + rowp * 192 + kc * 32 + (lane >> 4) * 8);
            whhr[nt] = *(const s8v*)(wcat + rowp * 192 + 64 + (lane >> 4) * 8);
        }
        s8v wgf[2];
#pragma unroll
        for (int kc = 0; kc < 2; ++kc)
            wgf[kc] = *(const s8v*)(wg + (16 * wvi + cx) * 64 + kc * 32 + (lane >> 4) * 8);

        float se_l = ((const float*)(ws + WS_SE))[16 * wvi + cx];
        float te_l = ((const float*)(ws + WS_TE))[16 * wvi + cx];
        float bias[8];
#pragma unroll
        for (int nt = 0; nt < 8; ++nt)
            bias[nt] = ((const float*)(ws + WS_BC))[128 * wvi + 16 * nt + cx];
        float spw0 = ((const float*)(ws + WS_SPW))[0];
        float spw1 = ((const float*)(ws + WS_SPW))[1];
        float pbe0 = ((const float*)(ws + WS_PBE))[0];
        float pbe1 = ((const float*)(ws + WS_PBE))[1];

        float creg[2][2][4];
#pragma unroll
        for (int mt = 0; mt < 2; ++mt)
#pragma unroll
            for (int jt = 0; jt < 2; ++jt)
#pragma unroll
                for (int rg = 0; rg < 4; ++rg)
                    creg[mt][jt][rg] = c0[(bk * 32 + 16 * mt + hi4 + rg) * 128 + 32 * wvi + 16 * jt + cx];

        // pre-loop: emb(0) on window 0 (already staged)
        {
            f4 accE[2];
            accE[0] = f4{0.f, 0.f, 0.f, 0.f};
            accE[1] = f4{0.f, 0.f, 0.f, 0.f};
#pragma unroll
            for (int kc = 0; kc < 2; ++kc)
#pragma unroll
                for (int mt = 0; mt < 2; ++mt) {
                    s8v a = *(const s8v*)(s_win + ((kc * 4 + (lane >> 4)) * 32 + 16 * mt + cx) * 8);
                    accE[mt] = __builtin_amdgcn_mfma_f32_16x16x32_bf16(a, wgf[kc], accE[mt], 0, 0, 0);
                }
            int e = 16 * wvi + cx;
#pragma unroll
            for (int mt = 0; mt < 2; ++mt)
#pragma unroll
                for (int rg = 0; rg < 4; ++rg) {
                    int a = 16 * mt + hi4 + rg;
                    float m = s_mr[0][a][0], r = s_mr[0][a][1];
                    float x = r * (accE[mt][rg] - m * se_l) + te_l;
                    x = fmaxf(x, 0.f) + 0.01f * fminf(x, 0.f);
                    s_x[((e >> 3) * 32 + a) * 8 + (e & 7)] = f2bf(x);
                }
            arrive(&s_sync[C_RDY]);
        }

#pragma unroll 1
        for (int t = 0; t < 30; ++t) {
            const int pc = t & 1, pn = pc ^ 1;
            waitge(&s_sync[C_RDY], (u32)(4 * (t + 1)));   // x(t),h(t) ready

            // gates GEMM in 2 jt-passes; pointwise fused per pass
#pragma unroll
            for (int jt = 0; jt < 2; ++jt) {
                f4 acc[2][4];
#pragma unroll
                for (int mt = 0; mt < 2; ++mt)
#pragma unroll
                    for (int g = 0; g < 4; ++g) {
                        float b = bias[2 * g + jt];
                        acc[mt][g] = f4{b, b, b, b};
                    }
#pragma unroll
                for (int kc = 0; kc < 6; ++kc) {
                    s8v a0, a1;
                    if (kc < 2) {
                        a0 = *(const s8v*)(s_x + ((pc * 8 + kc * 4 + (lane >> 4)) * 32 + cx) * 8);
                        a1 = *(const s8v*)(s_x + ((pc * 8 + kc * 4 + (lane >> 4)) * 32 + 16 + cx) * 8);
                    } else {
                        int ch = (kc - 2) * 4 + (lane >> 4);
                        a0 = *(const s8v*)(s_h + ((pc * 16 + ch) * 32 + cx) * 8);
                        a1 = *(const s8v*)(s_h + ((pc * 16 + ch) * 32 + 16 + cx) * 8);
                    }
#pragma unroll
                    for (int g = 0; g < 4; ++g) {
                        int nt = 2 * g + jt;
                        s8v b;
                        if (kc < 2) b = wih[nt][kc];
                        else if (kc == 2) b = whhr[nt];
                        else b = *(const s8v*)(s_whh + (((kc - 3) * 4 + (lane >> 4)) * 512 + 128 * wvi + 16 * nt + cx) * 8);
                        acc[0][g] = __builtin_amdgcn_mfma_f32_16x16x32_bf16(a0, b, acc[0][g], 0, 0, 0);
                        acc[1][g] = __builtin_amdgcn_mfma_f32_16x16x32_bf16(a1, b, acc[1][g], 0, 0, 0);
                    }
                }
                // LSTM pointwise for this jt -> creg, h(t+1) into s_h[pn]
                int kk = 32 * wvi + 16 * jt + cx;
                int ch = pn * 16 + (kk >> 3);
#pragma unroll
                for (int mt = 0; mt < 2; ++mt)
#pragma unroll
                    for (int rg = 0; rg < 4; ++rg) {
                        float iv = acc[mt][0][rg];
                        float fv = acc[mt][1][rg];
                        float gv = acc[mt][2][rg];
                        float ov = acc[mt][3][rg];
                        float si = __builtin_amdgcn_rcpf(1.f + __builtin_amdgcn_exp2f(-K1 * iv));
                        float sf = __builtin_amdgcn_rcpf(1.f + __builtin_amdgcn_exp2f(-K1 * fv));
                        float so = __builtin_amdgcn_rcpf(1.f + __builtin_amdgcn_exp2f(-K1 * ov));
                        float tg = 1.f - 2.f * __builtin_amdgcn_rcpf(1.f + __builtin_amdgcn_exp2f(K2 * gv));
                        float cn = sf * creg[mt][jt][rg] + si * tg;
                        creg[mt][jt][rg] = cn;
                        float tc = 1.f - 2.f * __builtin_amdgcn_rcpf(1.f + __builtin_amdgcn_exp2f(K2 * cn));
                        float hn = so * tc;
                        int a = 16 * mt + hi4 + rg;
                        s_h[(ch * 32 + a) * 8 + (cx & 7)] = f2bf(hn);
                    }
            }

            // stats via MFMA on own 32-col h slice (just written, same wave)
            {
                f4 d1[2], d2[2];
                d1[0] = f4{0.f, 0.f, 0.f, 0.f}; d1[1] = f4{0.f, 0.f, 0.f, 0.f};
                d2[0] = f4{0.f, 0.f, 0.f, 0.f}; d2[1] = f4{0.f, 0.f, 0.f, 0.f};
                s8v bfrag = *(const s8v*)(s_pwb + ((wvi * 4 + (lane >> 4)) * 16 + cx) * 8);
#pragma unroll
                for (int mt = 0; mt < 2; ++mt) {
                    s8v hf = *(const s8v*)(s_h + ((pn * 16 + 4 * wvi + (lane >> 4)) * 32 + 16 * mt + cx) * 8);
                    d1[mt] = __builtin_amdgcn_mfma_f32_16x16x32_bf16(hf, bfrag, d1[mt], 0, 0, 0);
                    d2[mt] = __builtin_amdgcn_mfma_f32_16x16x32_bf16(hf, hf, d2[mt], 0, 0, 0);
                }
#pragma unroll
                for (int mt = 0; mt < 2; ++mt) {
                    if (cx < 3) {
#pragma unroll
                        for (int rg = 0; rg < 4; ++rg)
                            s_red1[wvi][cx][mt * 16 + hi4 + rg] = d1[mt][rg];
                    }
                    if ((lane >> 4) == (cx >> 2))
                        s_red2[wvi][mt * 16 + cx] = d2[mt][cx & 3];
                }
            }
            arrive(&s_sync[C_RED]);

            // wv0: combine -> s_self (LDS only) -> C_PRD. No global store, no
            // vmcnt — wave 5 (staging group) publishes dout+flags off-path.
            if (wvi == 0) {
                waitge(&s_sync[C_RED], (u32)(4 * (t + 1)));
                int a = lane & 31, d = lane >> 5;
                float S0 = 0.f, S1 = 0.f, P = 0.f;
#pragma unroll
                for (int w = 0; w < 4; ++w) {
                    S0 += s_red1[w][0][a];
                    P  += s_red1[w][1 + d][a];
                    S1 += s_red2[w][a];
                }
                float m = S0 * (1.f / 128.f);
                float var = S1 * (1.f / 128.f) - m * m;
                float r = __builtin_amdgcn_rsqf(var + 1e-5f);
                float sp = (d == 0) ? spw0 : spw1;
                float pb = (d == 0) ? pbe0 : pbe1;
                float val = r * (P - m * sp) + pb;
                s_self[t & 1][2 * a + d] = val;
                if (tid == 0)
                    __hip_atomic_store(&s_sync[C_PRD], (u32)(t + 1), __ATOMIC_RELEASE, __HIP_MEMORY_SCOPE_WORKGROUP);
            }

            // emb(t+1) (pipelined; waits only on staging counters)
            if (t < 29) {
                waitge(&s_sync[C_WIN], (u32)(t + 1));
                waitge(&s_sync[C_STT], (u32)(t + 1));
                f4 accE[2];
                accE[0] = f4{0.f, 0.f, 0.f, 0.f};
                accE[1] = f4{0.f, 0.f, 0.f, 0.f};
#pragma unroll
                for (int kc = 0; kc < 2; ++kc)
#pragma unroll
                    for (int mt = 0; mt < 2; ++mt) {
                        s8v a = *(const s8v*)(s_win + ((pn * 8 + kc * 4 + (lane >> 4)) * 32 + 16 * mt + cx) * 8);
                        accE[mt] = __builtin_amdgcn_mfma_f32_16x16x32_bf16(a, wgf[kc], accE[mt], 0, 0, 0);
                    }
                int e = 16 * wvi + cx;
#pragma unroll
                for (int mt = 0; mt < 2; ++mt)
#pragma unroll
                    for (int rg = 0; rg < 4; ++rg) {
                        int a = 16 * mt + hi4 + rg;
                        float m = s_mr[pn][a][0], r = s_mr[pn][a][1];
                        float x = r * (accE[mt][rg] - m * se_l) + te_l;
                        x = fmaxf(x, 0.f) + 0.01f * fminf(x, 0.f);
                        s_x[((pn * 8 + (e >> 3)) * 32 + a) * 8 + (e & 7)] = f2bf(x);
                    }
            }
            arrive(&s_sync[C_RDY]);
        }
    } else {
        // ======================= STAGING GROUP (waves 4-7) =======================
        const int gt = tid - 256;

        auto stage_one = [&](int ci, int s, int pb) {
            int p = 16384 * s + 1280 * bk + 4 * ci;
            float v0, v1, v2, v3;
            if (p < 327680) {
                f4 vv = *(const f4*)(traj_rel + p);
                v0 = vv[0]; v1 = vv[1]; v2 = vv[2]; v3 = vv[3];
            } else if (bk == 255 && ci >= 304) {
                waitge(&s_sync[C_PRD], (u32)s);
                int o = 4 * ci - 1216;
                const float* sf = &s_self[(s - 1) & 1][0];
                v0 = sf[o]; v1 = sf[o + 1]; v2 = sf[o + 2]; v3 = sf[o + 3];
            } else {
                waitge(&s_sync[C_FLG], (u32)s);
                int q = p - 327680;
                f4 vv = *(const f4*)(dout + q);
                v0 = vv[0]; v1 = vv[1]; v2 = vv[2]; v3 = vv[3];
            }
            int a = ci / 10, kq = (ci % 10) * 4;
            u32 lo = (u32)f2bf(v0) | ((u32)f2bf(v1) << 16);
            u32 hh = (u32)f2bf(v2) | ((u32)f2bf(v3) << 16);
            u32* dst = (u32*)(s_win + ((pb * 8 + (kq >> 3)) * 32 + a) * 8 + (kq & 7));
            dst[0] = lo; dst[1] = hh;
            s_wp[ci] = f2{v0 + v1 + v2 + v3, v0 * v0 + v1 * v1 + v2 * v2 + v3 * v3};
        };

#pragma unroll 1
        for (int u = 0; u < 29; ++u) {
            const int pb = (u + 1) & 1;
            waitge(&s_sync[C_STT], (u32)u);          // s_wp free
            waitge(&s_sync[C_RDY], (u32)(4 * u));    // win/mr buffer free (emb(u-1) done)

            if (gt < 64) {
                int W0n = 16384 * (u + 1) + 1280 * bk;
                int Wend = W0n + 1280;
                if (Wend > 327680) {
                    int q0 = (W0n > 327680) ? (W0n - 327680) : 0;
                    int g = (q0 >> 6) + gt;
                    int gend = (Wend - 327681) >> 6;
                    if (g <= gend) {
                        int s = g >> 8, P = g & 255;
                        if (!(bk == 255 && P == 255)) {
                            while (__hip_atomic_load(&flags[P], __ATOMIC_RELAXED, __HIP_MEMORY_SCOPE_AGENT) <= s)
                                __builtin_amdgcn_s_sleep(2);
                        }
                    }
                }
                if (gt == 0)
                    __hip_atomic_store(&s_sync[C_FLG], (u32)(u + 1), __ATOMIC_RELEASE, __HIP_MEMORY_SCOPE_WORKGROUP);
            }

            stage_one(gt, u + 1, pb);
            if (gt < 64) stage_one(gt + 256, u + 1, pb);

            arrive(&s_sync[C_SWP]);

            // wave 5: output publisher for step u (off every compute path)
            if ((gt >> 6) == 1) {
                waitge(&s_sync[C_PRD], (u32)(u + 1));
                float val = s_self[u & 1][gt & 63];
                __hip_atomic_store(dout + u * 16384 + bk * 64 + (gt & 63), val,
                                   __ATOMIC_RELAXED, __HIP_MEMORY_SCOPE_AGENT);
                asm volatile("s_waitcnt vmcnt(0)" ::: "memory");
                if (gt == 64)
                    __hip_atomic_store(&flags[bk], u + 1, __ATOMIC_RELAXED, __HIP_MEMORY_SCOPE_AGENT);
            }

            if (gt < 64) {
                waitge(&s_sync[C_SWP], (u32)(4 * (u + 1)));
                if (gt == 0)
                    __hip_atomic_store(&s_sync[C_WIN], (u32)(u + 1), __ATOMIC_RELEASE, __HIP_MEMORY_SCOPE_WORKGROUP);
                if (gt < 32) {
                    float s = 0.f, s2 = 0.f;
#pragma unroll
                    for (int u2 = 0; u2 < 10; ++u2) {
                        f2 pp = s_wp[gt * 10 + u2];
                        s += pp[0]; s2 += pp[1];
                    }
                    float m = s * (1.0f / 40.0f);
                    float var = s2 * (1.0f / 40.0f) - m * m;
                    s_mr[pb][gt][0] = m;
                    s_mr[pb][gt][1] = __builtin_amdgcn_rsqf(var + 1e-5f);
                }
                if (gt == 0)
                    __hip_atomic_store(&s_sync[C_STT], (u32)(u + 1), __ATOMIC_RELEASE, __HIP_MEMORY_SCOPE_WORKGROUP);
            }
        }

        // wave 5 epilogue: publish final step (t=29) outputs
        if ((gt >> 6) == 1) {
            waitge(&s_sync[C_PRD], 30u);
            float val = s_self[1][gt & 63];   // 29 & 1
            __hip_atomic_store(dout + 29 * 16384 + bk * 64 + (gt & 63), val,
                               __ATOMIC_RELAXED, __HIP_MEMORY_SCOPE_AGENT);
        }
    }
}

extern "C" void kernel_launch(void* const* d_in, const int* in_sizes, int n_in,
                              void* d_out, int out_size, void* d_ws, size_t ws_size,
                              hipStream_t stream) {
    (void)in_sizes; (void)n_in; (void)out_size; (void)ws_size;
    const float* traj_rel = (const float*)d_in[1];
    const float* h0 = (const float*)d_in[2];
    const float* c0 = (const float*)d_in[3];
    const float* ln1w = (const float*)d_in[4];
    const float* ln1b = (const float*)d_in[5];
    const float* embW = (const float*)d_in[6];
    const float* embB = (const float*)d_in[7];
    const float* Wih = (const float*)d_in[8];
    const float* Whh = (const float*)d_in[9];
    const float* bih = (const float*)d_in[10];
    const float* bhh = (const float*)d_in[11];
    const float* ln2w = (const float*)d_in[12];
    const float* ln2b = (const float*)d_in[13];
    const float* posW = (const float*)d_in[14];
    const float* posB = (const float*)d_in[15];
    char* ws = (char*)d_ws;

    hipLaunchKernelGGL(prep_kernel, dim3(33), dim3(256), 0, stream,
                       ln1w, ln1b, embW, embB, Wih, Whh, bih, bhh, ln2w, ln2b, posW, posB, ws);
    hipLaunchKernelGGL(lstm_kernel, dim3(256), dim3(512), 0, stream,
                       traj_rel, h0, c0, (float*)d_out, ws);
}

// Round 11
// 140.841 us; speedup vs baseline: 1.1957x; 1.0216x over previous
//
#include <hip/hip_runtime.h>
#include <hip/hip_bf16.h>
#include <stdint.h>

#define K1 1.4426950408889634f
#define K2 2.8853900817779268f

typedef float f4 __attribute__((ext_vector_type(4)));
typedef float f2 __attribute__((ext_vector_type(2)));
typedef short s8v __attribute__((ext_vector_type(8)));
typedef unsigned int u32;
typedef unsigned short u16;

// workspace offsets (bytes)
#define WS_WCAT  0        // u16[512*192] permuted+concat gate weights (bf16)
#define WS_WG    196608   // u16[64*64]   ln1-folded emb weights, k-padded (bf16)
#define WS_TE    204800   // f32[64]
#define WS_SE    205056   // f32[64]
#define WS_PWLN  205312   // f32[256]  pos_W * ln2_w
#define WS_SPW   206336   // f32[2]
#define WS_PBE   206344   // f32[2]
#define WS_BC    206352   // f32[512]  permuted b_ih+b_hh
#define WS_FLAGS 208400   // int[256] per-block step progress

// LDS sync cells
#define C_WIN 0   // windows staged through v (wave4 lane0)
#define C_RDY 1   // 4*(steps whose x,h are ready) — compute arrivals
#define C_RED 2   // 4*(t+1) stats partials written
#define C_SWP 3   // staging internal, 4/iter
#define C_STT 4   // window stats ready through v (wave4 lane0)
#define C_PRD 5   // steps whose outputs are in s_self (wv0)
#define C_FLG 6   // producer flags confirmed for window v (wave4 lane0)

__device__ __forceinline__ u16 f2bf(float x) {
    u32 u = __builtin_bit_cast(u32, x);
    u32 r = (u + 0x7FFFu + ((u >> 16) & 1u)) >> 16;
    return (u16)r;
}
__device__ __forceinline__ float bf2f(u16 h) {
    u32 u = ((u32)h) << 16;
    return __builtin_bit_cast(float, u);
}

// tight spin: for compute-critical handoffs (latency matters)
__device__ __forceinline__ void waitge(u32* c, u32 v) {
    while (__hip_atomic_load(c, __ATOMIC_ACQUIRE, __HIP_MEMORY_SCOPE_WORKGROUP) < v) {}
}
// sleeping spin: for slack-side waits — spinning waves must not steal
// DS-pipe issue slots from the compute waves on the same CU.
__device__ __forceinline__ void waitge_s(u32* c, u32 v) {
    if (__hip_atomic_load(c, __ATOMIC_ACQUIRE, __HIP_MEMORY_SCOPE_WORKGROUP) >= v) return;
    do {
        __builtin_amdgcn_s_sleep(1);
    } while (__hip_atomic_load(c, __ATOMIC_ACQUIRE, __HIP_MEMORY_SCOPE_WORKGROUP) < v);
}
__device__ __forceinline__ void arrive(u32* c) {
    if ((threadIdx.x & 63) == 0)
        __hip_atomic_fetch_add(c, 1u, __ATOMIC_RELEASE, __HIP_MEMORY_SCOPE_WORKGROUP);
}

__global__ void prep_kernel(const float* __restrict__ ln1w, const float* __restrict__ ln1b,
                            const float* __restrict__ embW, const float* __restrict__ embB,
                            const float* __restrict__ Wih, const float* __restrict__ Whh,
                            const float* __restrict__ bih, const float* __restrict__ bhh,
                            const float* __restrict__ ln2w, const float* __restrict__ ln2b,
                            const float* __restrict__ posW, const float* __restrict__ posB,
                            char* __restrict__ ws) {
    const int tid = threadIdx.x;
    const int bid = blockIdx.x;
    u16* wcat = (u16*)(ws + WS_WCAT);

    if (bid > 0) {
        int base = (bid - 1) * 3072;
#pragma unroll 4
        for (int i = 0; i < 12; ++i) {
            int idx = base + i * 256 + tid;
            int np = idx / 192, k = idx % 192;
            int w = np >> 7, r = np & 127, nt = r >> 4, c = r & 15;
            int g = nt >> 1, jt = nt & 1;
            int n0 = (g << 7) | (w << 5) | (jt << 4) | c;
            float v = (k < 64) ? Wih[n0 * 64 + k] : Whh[n0 * 128 + (k - 64)];
            wcat[idx] = f2bf(v);
        }
        return;
    }

    u16* wg   = (u16*)(ws + WS_WG);
    float* te = (float*)(ws + WS_TE);
    float* se = (float*)(ws + WS_SE);
    float* pwln = (float*)(ws + WS_PWLN);
    float* spw  = (float*)(ws + WS_SPW);
    float* pbe  = (float*)(ws + WS_PBE);
    float* bc   = (float*)(ws + WS_BC);
    int* flags  = (int*)(ws + WS_FLAGS);
    __shared__ float pp[2][4];

    for (int idx = tid; idx < 64 * 64; idx += 256) {
        int e = idx >> 6, k = idx & 63;
        float v = (k < 40) ? embW[e * 40 + k] * ln1w[k] : 0.0f;
        wg[idx] = f2bf(v);
    }
    if (tid < 64) {
        int e = tid;
        float t = embB[e], s = 0.f;
        for (int k = 0; k < 40; ++k) {
            t += embW[e * 40 + k] * ln1b[k];
            s += bf2f(f2bf(embW[e * 40 + k] * ln1w[k]));
        }
        te[e] = t; se[e] = s;
    }
    if (tid >= 64 && tid < 192) {
        int j = tid - 64;
        float a0 = posW[j] * ln2w[j],      a1 = posW[128 + j] * ln2w[j];
        float b0 = posW[j] * ln2b[j],      b1 = posW[128 + j] * ln2b[j];
        pwln[j] = a0; pwln[128 + j] = a1;
#pragma unroll
        for (int m = 1; m < 64; m <<= 1) {
            a0 += __shfl_xor(a0, m, 64); a1 += __shfl_xor(a1, m, 64);
            b0 += __shfl_xor(b0, m, 64); b1 += __shfl_xor(b1, m, 64);
        }
        if ((tid & 63) == 0) {
            int wv = (tid >> 6) - 1;
            pp[wv][0] = a0; pp[wv][1] = a1; pp[wv][2] = b0; pp[wv][3] = b1;
        }
    }
    for (int idx = tid; idx < 512; idx += 256) {
        int w = idx >> 7, r = idx & 127, nt = r >> 4, c = r & 15;
        int g = nt >> 1, jt = nt & 1;
        int n0 = (g << 7) | (w << 5) | (jt << 4) | c;
        bc[idx] = bih[n0] + bhh[n0];
    }
    flags[tid] = 0;
    __syncthreads();
    if (tid == 0) {
        spw[0] = pp[0][0] + pp[1][0];
        spw[1] = pp[0][1] + pp[1][1];
        pbe[0] = posB[0] + pp[0][2] + pp[1][2];
        pbe[1] = posB[1] + pp[0][3] + pp[1][3];
    }
}

__global__ __launch_bounds__(512, 1)
void lstm_kernel(const float* __restrict__ traj_rel,
                 const float* __restrict__ h0, const float* __restrict__ c0,
                 float* __restrict__ dout, char* __restrict__ ws) {
    __shared__ __align__(16) u16 s_whh[12 * 512 * 8];   // 98304 B: W_hh k-chunks 3..5
    __shared__ __align__(16) u16 s_x[2 * 8 * 32 * 8];   // 8192 B
    __shared__ __align__(16) u16 s_h[2 * 16 * 32 * 8];  // 16384 B
    __shared__ __align__(16) u16 s_win[2 * 8 * 32 * 8]; // 8192 B
    __shared__ __align__(16) u16 s_pwb[2048];           // 4096 B : stats B-frags per wave
    __shared__ __align__(16) float s_red1[4][4][32];    // 2048 B : D1 partials [w][n][a]
    __shared__ __align__(16) float s_red2[4][32];       // 512 B  : D2 diag partials
    __shared__ __align__(16) f2 s_wp[320];              // 2560 B
    __shared__ float s_mr[2][32][2];                    // 512 B
    __shared__ float s_self[2][64];                     // 512 B : step outputs (dbuf)
    __shared__ u32 s_sync[8];

    const int tid = threadIdx.x;
    const int bk = blockIdx.x;
    const int lane = tid & 63;

    const u16* wcat = (const u16*)(ws + WS_WCAT);
    const u16* wg = (const u16*)(ws + WS_WG);
    int* flags = (int*)(ws + WS_FLAGS);

    if (tid == 0) {
        s_sync[C_WIN] = 0; s_sync[C_RDY] = 0; s_sync[C_RED] = 0;
        s_sync[C_SWP] = 0; s_sync[C_STT] = 0; s_sync[C_PRD] = 0;
        s_sync[C_FLG] = 0;
    }
    // stage W_hh k-chunks 3..5 -> LDS
    for (int idx = tid; idx < 12 * 512; idx += 512) {
        const u16* src = wcat + (idx & 511) * 192 + 96 + (idx >> 9) * 8;
        *(s8v*)(s_whh + idx * 8) = *(const s8v*)src;
    }
    // stats B-frags: [w][ksub][n][8] ; n=0:ones, 1:pwl0, 2:pwl1, 3..:zero
    {
        const float* pwln = (const float*)(ws + WS_PWLN);
        for (int idx = tid; idx < 2048; idx += 512) {
            int w = idx >> 9, rem = idx & 511;
            int ksub = rem >> 7, rem2 = rem & 127;
            int n = rem2 >> 3, i = rem2 & 7;
            int j = 32 * w + ksub * 8 + i;
            float v = (n == 0) ? 1.0f : (n == 1) ? pwln[j] : (n == 2) ? pwln[128 + j] : 0.0f;
            s_pwb[(((w * 4 + ksub) * 16) + n) * 8 + i] = f2bf(v);
        }
    }
    // zero window pad chunks (k=40..63), both buffers
    if (tid < 192) {
        int pb = tid / 96, r = tid % 96;
        int ch = 5 + r / 32, a = r & 31;
        s8v z = {0, 0, 0, 0, 0, 0, 0, 0};
        *(s8v*)(s_win + ((pb * 8 + ch) * 32 + a) * 8) = z;
    }
    // win[0] stage
    if (tid < 320) {
        int p = 1280 * bk + 4 * tid;
        f4 v = *(const f4*)(traj_rel + p);
        int a = tid / 10, kq = (tid % 10) * 4;
        u32 lo = (u32)f2bf(v[0]) | ((u32)f2bf(v[1]) << 16);
        u32 hh = (u32)f2bf(v[2]) | ((u32)f2bf(v[3]) << 16);
        u32* dst = (u32*)(s_win + ((kq >> 3) * 32 + a) * 8 + (kq & 7));
        dst[0] = lo; dst[1] = hh;
        s_wp[tid] = f2{v[0] + v[1] + v[2] + v[3],
                       v[0] * v[0] + v[1] * v[1] + v[2] * v[2] + v[3] * v[3]};
    }
    // h0 -> s_h buffer 0
    if (tid < 256) {
        int a = tid & 31, q = tid >> 5;
        const float* hp = h0 + (bk * 32 + a) * 128 + q * 16;
        u16 hb[16];
#pragma unroll
        for (int u = 0; u < 16; ++u) hb[u] = f2bf(hp[u]);
#pragma unroll
        for (int half = 0; half < 2; ++half) {
            s8v v;
#pragma unroll
            for (int u = 0; u < 8; ++u) v[u] = (short)hb[half * 8 + u];
            *(s8v*)(s_h + ((2 * q + half) * 32 + a) * 8) = v;
        }
    }
    __syncthreads();
    if (tid < 32) {
        float s = 0.f, s2 = 0.f;
#pragma unroll
        for (int u = 0; u < 10; ++u) {
            f2 p = s_wp[tid * 10 + u];
            s += p[0]; s2 += p[1];
        }
        float m = s * (1.0f / 40.0f);
        float var = s2 * (1.0f / 40.0f) - m * m;
        s_mr[0][tid][0] = m;
        s_mr[0][tid][1] = __builtin_amdgcn_rsqf(var + 1e-5f);
    }
    __syncthreads();   // groups diverge below

    if (tid < 256) {
        // ======================= COMPUTE GROUP (waves 0-3) =======================
        const int wvi = tid >> 6;
        const int cx = lane & 15;
        const int hi4 = (lane >> 4) * 4;

        s8v wih[8][2], whhr[8];
#pragma unroll
        for (int nt = 0; nt < 8; ++nt) {
            int rowp = 128 * wvi + 16 * nt + cx;
#pragma unroll
            for (int kc = 0; kc < 2; ++kc)
                wih[nt][kc] = *(const s8v*)(wcat + rowp * 192 + kc * 32 + (lane >> 4) * 8);
            whhr[nt] = *(const s8v*)(wcat + rowp * 192 + 64 + (lane >> 4) * 8);
        }
        s8v wgf[2];
#pragma unroll
        for (int kc = 0; kc < 2; ++kc)
            wgf[kc] = *(const s8v*)(wg + (16 * wvi + cx) * 64 + kc * 32 + (lane >> 4) * 8);

        float se_l = ((const float*)(ws + WS_SE))[16 * wvi + cx];
        float te_l = ((const float*)(ws + WS_TE))[16 * wvi + cx];
        float bias[8];
#pragma unroll
        for (int nt = 0; nt < 8; ++nt)
            bias[nt] = ((const float*)(ws + WS_BC))[128 * wvi + 16 * nt + cx];
        float spw0 = ((const float*)(ws + WS_SPW))[0];
        float spw1 = ((const float*)(ws + WS_SPW))[1];
        float pbe0 = ((const float*)(ws + WS_PBE))[0];
        float pbe1 = ((const float*)(ws + WS_PBE))[1];

        float creg[2][2][4];
#pragma unroll
        for (int mt = 0; mt < 2; ++mt)
#pragma unroll
            for (int jt = 0; jt < 2; ++jt)
#pragma unroll
                for (int rg = 0; rg < 4; ++rg)
                    creg[mt][jt][rg] = c0[(bk * 32 + 16 * mt + hi4 + rg) * 128 + 32 * wvi + 16 * jt + cx];

        // pre-loop: emb(0) on window 0 (already staged)
        {
            f4 accE[2];
            accE[0] = f4{0.f, 0.f, 0.f, 0.f};
            accE[1] = f4{0.f, 0.f, 0.f, 0.f};
#pragma unroll
            for (int kc = 0; kc < 2; ++kc)
#pragma unroll
                for (int mt = 0; mt < 2; ++mt) {
                    s8v a = *(const s8v*)(s_win + ((kc * 4 + (lane >> 4)) * 32 + 16 * mt + cx) * 8);
                    accE[mt] = __builtin_amdgcn_mfma_f32_16x16x32_bf16(a, wgf[kc], accE[mt], 0, 0, 0);
                }
            int e = 16 * wvi + cx;
#pragma unroll
            for (int mt = 0; mt < 2; ++mt)
#pragma unroll
                for (int rg = 0; rg < 4; ++rg) {
                    int a = 16 * mt + hi4 + rg;
                    float m = s_mr[0][a][0], r = s_mr[0][a][1];
                    float x = r * (accE[mt][rg] - m * se_l) + te_l;
                    x = fmaxf(x, 0.f) + 0.01f * fminf(x, 0.f);
                    s_x[((e >> 3) * 32 + a) * 8 + (e & 7)] = f2bf(x);
                }
            arrive(&s_sync[C_RDY]);
        }

#pragma unroll 1
        for (int t = 0; t < 30; ++t) {
            const int pc = t & 1, pn = pc ^ 1;
            waitge(&s_sync[C_RDY], (u32)(4 * (t + 1)));   // x(t),h(t) ready

            // gates GEMM in 2 jt-passes; pointwise fused per pass
#pragma unroll
            for (int jt = 0; jt < 2; ++jt) {
                f4 acc[2][4];
#pragma unroll
                for (int mt = 0; mt < 2; ++mt)
#pragma unroll
                    for (int g = 0; g < 4; ++g) {
                        float b = bias[2 * g + jt];
                        acc[mt][g] = f4{b, b, b, b};
                    }
#pragma unroll
                for (int kc = 0; kc < 6; ++kc) {
                    s8v a0, a1;
                    if (kc < 2) {
                        a0 = *(const s8v*)(s_x + ((pc * 8 + kc * 4 + (lane >> 4)) * 32 + cx) * 8);
                        a1 = *(const s8v*)(s_x + ((pc * 8 + kc * 4 + (lane >> 4)) * 32 + 16 + cx) * 8);
                    } else {
                        int ch = (kc - 2) * 4 + (lane >> 4);
                        a0 = *(const s8v*)(s_h + ((pc * 16 + ch) * 32 + cx) * 8);
                        a1 = *(const s8v*)(s_h + ((pc * 16 + ch) * 32 + 16 + cx) * 8);
                    }
#pragma unroll
                    for (int g = 0; g < 4; ++g) {
                        int nt = 2 * g + jt;
                        s8v b;
                        if (kc < 2) b = wih[nt][kc];
                        else if (kc == 2) b = whhr[nt];
                        else b = *(const s8v*)(s_whh + (((kc - 3) * 4 + (lane >> 4)) * 512 + 128 * wvi + 16 * nt + cx) * 8);
                        acc[0][g] = __builtin_amdgcn_mfma_f32_16x16x32_bf16(a0, b, acc[0][g], 0, 0, 0);
                        acc[1][g] = __builtin_amdgcn_mfma_f32_16x16x32_bf16(a1, b, acc[1][g], 0, 0, 0);
                    }
                }
                // LSTM pointwise for this jt -> creg, h(t+1) into s_h[pn]
                int kk = 32 * wvi + 16 * jt + cx;
                int ch = pn * 16 + (kk >> 3);
#pragma unroll
                for (int mt = 0; mt < 2; ++mt)
#pragma unroll
                    for (int rg = 0; rg < 4; ++rg) {
                        float iv = acc[mt][0][rg];
                        float fv = acc[mt][1][rg];
                        float gv = acc[mt][2][rg];
                        float ov = acc[mt][3][rg];
                        float si = __builtin_amdgcn_rcpf(1.f + __builtin_amdgcn_exp2f(-K1 * iv));
                        float sf = __builtin_amdgcn_rcpf(1.f + __builtin_amdgcn_exp2f(-K1 * fv));
                        float so = __builtin_amdgcn_rcpf(1.f + __builtin_amdgcn_exp2f(-K1 * ov));
                        float tg = 1.f - 2.f * __builtin_amdgcn_rcpf(1.f + __builtin_amdgcn_exp2f(K2 * gv));
                        float cn = sf * creg[mt][jt][rg] + si * tg;
                        creg[mt][jt][rg] = cn;
                        float tc = 1.f - 2.f * __builtin_amdgcn_rcpf(1.f + __builtin_amdgcn_exp2f(K2 * cn));
                        float hn = so * tc;
                        int a = 16 * mt + hi4 + rg;
                        s_h[(ch * 32 + a) * 8 + (cx & 7)] = f2bf(hn);
                    }
            }

            // stats via MFMA on own 32-col h slice (just written, same wave)
            {
                f4 d1[2], d2[2];
                d1[0] = f4{0.f, 0.f, 0.f, 0.f}; d1[1] = f4{0.f, 0.f, 0.f, 0.f};
                d2[0] = f4{0.f, 0.f, 0.f, 0.f}; d2[1] = f4{0.f, 0.f, 0.f, 0.f};
                s8v bfrag = *(const s8v*)(s_pwb + ((wvi * 4 + (lane >> 4)) * 16 + cx) * 8);
#pragma unroll
                for (int mt = 0; mt < 2; ++mt) {
                    s8v hf = *(const s8v*)(s_h + ((pn * 16 + 4 * wvi + (lane >> 4)) * 32 + 16 * mt + cx) * 8);
                    d1[mt] = __builtin_amdgcn_mfma_f32_16x16x32_bf16(hf, bfrag, d1[mt], 0, 0, 0);
                    d2[mt] = __builtin_amdgcn_mfma_f32_16x16x32_bf16(hf, hf, d2[mt], 0, 0, 0);
                }
#pragma unroll
                for (int mt = 0; mt < 2; ++mt) {
                    if (cx < 3) {
#pragma unroll
                        for (int rg = 0; rg < 4; ++rg)
                            s_red1[wvi][cx][mt * 16 + hi4 + rg] = d1[mt][rg];
                    }
                    if ((lane >> 4) == (cx >> 2))
                        s_red2[wvi][mt * 16 + cx] = d2[mt][cx & 3];
                }
            }
            arrive(&s_sync[C_RED]);

            // wv0: combine -> s_self (LDS only) -> C_PRD. No global store, no
            // vmcnt — wave 5 (staging group) publishes dout+flags off-path.
            if (wvi == 0) {
                waitge(&s_sync[C_RED], (u32)(4 * (t + 1)));
                int a = lane & 31, d = lane >> 5;
                float S0 = 0.f, S1 = 0.f, P = 0.f;
#pragma unroll
                for (int w = 0; w < 4; ++w) {
                    S0 += s_red1[w][0][a];
                    P  += s_red1[w][1 + d][a];
                    S1 += s_red2[w][a];
                }
                float m = S0 * (1.f / 128.f);
                float var = S1 * (1.f / 128.f) - m * m;
                float r = __builtin_amdgcn_rsqf(var + 1e-5f);
                float sp = (d == 0) ? spw0 : spw1;
                float pb = (d == 0) ? pbe0 : pbe1;
                float val = r * (P - m * sp) + pb;
                s_self[t & 1][2 * a + d] = val;
                if (tid == 0)
                    __hip_atomic_store(&s_sync[C_PRD], (u32)(t + 1), __ATOMIC_RELEASE, __HIP_MEMORY_SCOPE_WORKGROUP);
            }

            // emb(t+1) (pipelined; waits only on staging counters)
            if (t < 29) {
                waitge(&s_sync[C_WIN], (u32)(t + 1));
                waitge(&s_sync[C_STT], (u32)(t + 1));
                f4 accE[2];
                accE[0] = f4{0.f, 0.f, 0.f, 0.f};
                accE[1] = f4{0.f, 0.f, 0.f, 0.f};
#pragma unroll
                for (int kc = 0; kc < 2; ++kc)
#pragma unroll
                    for (int mt = 0; mt < 2; ++mt) {
                        s8v a = *(const s8v*)(s_win + ((pn * 8 + kc * 4 + (lane >> 4)) * 32 + 16 * mt + cx) * 8);
                        accE[mt] = __builtin_amdgcn_mfma_f32_16x16x32_bf16(a, wgf[kc], accE[mt], 0, 0, 0);
                    }
                int e = 16 * wvi + cx;
#pragma unroll
                for (int mt = 0; mt < 2; ++mt)
#pragma unroll
                    for (int rg = 0; rg < 4; ++rg) {
                        int a = 16 * mt + hi4 + rg;
                        float m = s_mr[pn][a][0], r = s_mr[pn][a][1];
                        float x = r * (accE[mt][rg] - m * se_l) + te_l;
                        x = fmaxf(x, 0.f) + 0.01f * fminf(x, 0.f);
                        s_x[((pn * 8 + (e >> 3)) * 32 + a) * 8 + (e & 7)] = f2bf(x);
                    }
            }
            arrive(&s_sync[C_RDY]);
        }
    } else {
        // ======================= STAGING GROUP (waves 4-7) =======================
        const int gt = tid - 256;

        auto stage_one = [&](int ci, int s, int pb) {
            int p = 16384 * s + 1280 * bk + 4 * ci;
            float v0, v1, v2, v3;
            if (p < 327680) {
                f4 vv = *(const f4*)(traj_rel + p);
                v0 = vv[0]; v1 = vv[1]; v2 = vv[2]; v3 = vv[3];
            } else if (bk == 255 && ci >= 304) {
                waitge_s(&s_sync[C_PRD], (u32)s);
                int o = 4 * ci - 1216;
                const float* sf = &s_self[(s - 1) & 1][0];
                v0 = sf[o]; v1 = sf[o + 1]; v2 = sf[o + 2]; v3 = sf[o + 3];
            } else {
                waitge_s(&s_sync[C_FLG], (u32)s);
                int q = p - 327680;
                f4 vv = *(const f4*)(dout + q);
                v0 = vv[0]; v1 = vv[1]; v2 = vv[2]; v3 = vv[3];
            }
            int a = ci / 10, kq = (ci % 10) * 4;
            u32 lo = (u32)f2bf(v0) | ((u32)f2bf(v1) << 16);
            u32 hh = (u32)f2bf(v2) | ((u32)f2bf(v3) << 16);
            u32* dst = (u32*)(s_win + ((pb * 8 + (kq >> 3)) * 32 + a) * 8 + (kq & 7));
            dst[0] = lo; dst[1] = hh;
            s_wp[ci] = f2{v0 + v1 + v2 + v3, v0 * v0 + v1 * v1 + v2 * v2 + v3 * v3};
        };

#pragma unroll 1
        for (int u = 0; u < 29; ++u) {
            const int pb = (u + 1) & 1;
            waitge_s(&s_sync[C_STT], (u32)u);          // s_wp free
            waitge_s(&s_sync[C_RDY], (u32)(4 * u));    // win/mr buffer free (emb(u-1) done)

            if (gt < 64) {
                int W0n = 16384 * (u + 1) + 1280 * bk;
                int Wend = W0n + 1280;
                if (Wend > 327680) {
                    int q0 = (W0n > 327680) ? (W0n - 327680) : 0;
                    int g = (q0 >> 6) + gt;
                    int gend = (Wend - 327681) >> 6;
                    if (g <= gend) {
                        int s = g >> 8, P = g & 255;
                        if (!(bk == 255 && P == 255)) {
                            while (__hip_atomic_load(&flags[P], __ATOMIC_RELAXED, __HIP_MEMORY_SCOPE_AGENT) <= s)
                                __builtin_amdgcn_s_sleep(2);
                        }
                    }
                }
                if (gt == 0)
                    __hip_atomic_store(&s_sync[C_FLG], (u32)(u + 1), __ATOMIC_RELEASE, __HIP_MEMORY_SCOPE_WORKGROUP);
            }

            stage_one(gt, u + 1, pb);
            if (gt < 64) stage_one(gt + 256, u + 1, pb);

            arrive(&s_sync[C_SWP]);

            // wave 5: output publisher for step u (off every compute path)
            if ((gt >> 6) == 1) {
                waitge_s(&s_sync[C_PRD], (u32)(u + 1));
                float val = s_self[u & 1][gt & 63];
                __hip_atomic_store(dout + u * 16384 + bk * 64 + (gt & 63), val,
                                   __ATOMIC_RELAXED, __HIP_MEMORY_SCOPE_AGENT);
                asm volatile("s_waitcnt vmcnt(0)" ::: "memory");
                if (gt == 64)
                    __hip_atomic_store(&flags[bk], u + 1, __ATOMIC_RELAXED, __HIP_MEMORY_SCOPE_AGENT);
            }

            if (gt < 64) {
                waitge_s(&s_sync[C_SWP], (u32)(4 * (u + 1)));
                if (gt == 0)
                    __hip_atomic_store(&s_sync[C_WIN], (u32)(u + 1), __ATOMIC_RELEASE, __HIP_MEMORY_SCOPE_WORKGROUP);
                if (gt < 32) {
                    float s = 0.f, s2 = 0.f;
#pragma unroll
                    for (int u2 = 0; u2 < 10; ++u2) {
                        f2 pp = s_wp[gt * 10 + u2];
                        s += pp[0]; s2 += pp[1];
                    }
                    float m = s * (1.0f / 40.0f);
                    float var = s2 * (1.0f / 40.0f) - m * m;
                    s_mr[pb][gt][0] = m;
                    s_mr[pb][gt][1] = __builtin_amdgcn_rsqf(var + 1e-5f);
                }
                if (gt == 0)
                    __hip_atomic_store(&s_sync[C_STT], (u32)(u + 1), __ATOMIC_RELEASE, __HIP_MEMORY_SCOPE_WORKGROUP);
            }
        }

        // wave 5 epilogue: publish final step (t=29) outputs
        if ((gt >> 6) == 1) {
            waitge_s(&s_sync[C_PRD], 30u);
            float val = s_self[1][gt & 63];   // 29 & 1
            __hip_atomic_store(dout + 29 * 16384 + bk * 64 + (gt & 63), val,
                               __ATOMIC_RELAXED, __HIP_MEMORY_SCOPE_AGENT);
        }
    }
}

extern "C" void kernel_launch(void* const* d_in, const int* in_sizes, int n_in,
                              void* d_out, int out_size, void* d_ws, size_t ws_size,
                              hipStream_t stream) {
    (void)in_sizes; (void)n_in; (void)out_size; (void)ws_size;
    const float* traj_rel = (const float*)d_in[1];
    const float* h0 = (const float*)d_in[2];
    const float* c0 = (const float*)d_in[3];
    const float* ln1w = (const float*)d_in[4];
    const float* ln1b = (const float*)d_in[5];
    const float* embW = (const float*)d_in[6];
    const float* embB = (const float*)d_in[7];
    const float* Wih = (const float*)d_in[8];
    const float* Whh = (const float*)d_in[9];
    const float* bih = (const float*)d_in[10];
    const float* bhh = (const float*)d_in[11];
    const float* ln2w = (const float*)d_in[12];
    const float* ln2b = (const float*)d_in[13];
    const float* posW = (const float*)d_in[14];
    const float* posB = (const float*)d_in[15];
    char* ws = (char*)d_ws;

    hipLaunchKernelGGL(prep_kernel, dim3(33), dim3(256), 0, stream,
                       ln1w, ln1b, embW, embB, Wih, Whh, bih, bhh, ln2w, ln2b, posW, posB, ws);
    hipLaunchKernelGGL(lstm_kernel, dim3(256), dim3(512), 0, stream,
                       traj_rel, h0, c0, (float*)d_out, ws);
}